// Round 5
// baseline (77.190 us; speedup 1.0000x reference)
//
#include <hip/hip_runtime.h>
#include <math.h>

#define LOG2E 1.44269504088896340736f

constexpr int IMG = 64;   // image stride (64x64)
constexpr int OW  = 62;   // output width/height
constexpr int D   = 32;
constexpr int K   = 4;

// Transformed-constant entry, 32 floats per (k,d):
//  [0..7]   lr[8]  = log2(s1_j/s0_j) for binary j in {0,1,2,3,5,6,7,8}
//  [8]      cB     = sum_j log2(s0_j) + log2(s1_4)   (center forced to 1)
//  [9..17]  Wc[9]  = -10*log2e*W1_j   (analog)
//  [18..26] qc[9]  =  10*log2e*q1_j
//  [27..31] pad
__global__ void build_table(const float* __restrict__ Wm,
                            const float* __restrict__ qm,
                            float* __restrict__ tb,
                            float* __restrict__ out, int out_n)
{
    const int t = threadIdx.x;
    for (int i = t; i < out_n; i += 128) out[i] = 0.f;   // replaces memset dispatch
    if (t >= K * D) return;
    const int d = t & 31;
    const int k = t >> 5;
    const int base = d * 72;
    float* e = tb + t * 32;

    float cB = 0.f;
    int jj = 0;
#pragma unroll
    for (int j = 0; j < 9; ++j) {
        const float w0 = Wm[base + j * 4 + k];
        const float q0 = qm[base + j * 4 + k];
        // log2(sigmoid(z)) = -log2(1 + exp(-z))
        const float l1 = -log2f(1.f + __builtin_amdgcn_exp2f(-10.f * LOG2E * (w0 - q0)));
        if (j == 4) {
            cB += l1;
        } else {
            const float l0 = -log2f(1.f + __builtin_amdgcn_exp2f(10.f * LOG2E * q0));
            cB += l0;
            e[jj++] = l1 - l0;
        }
        const float w1 = Wm[base + (9 + j) * 4 + k];
        const float q1 = qm[base + (9 + j) * 4 + k];
        e[9 + j]  = -10.f * LOG2E * w1;
        e[18 + j] =  10.f * LOG2E * q1;
    }
    e[8] = cB;
    e[27] = e[28] = e[29] = e[30] = e[31] = 0.f;
}

// butterfly-add stage via DPP (VALU, no LDS traffic); ctrl must be a
// compile-time constant -> template parameter.
template <int CTRL>
__device__ __forceinline__ float dpp_xadd(float v) {
    const int t = __builtin_amdgcn_update_dpp(0, __float_as_int(v), CTRL, 0xf, 0xf, true);
    return v + __int_as_float(t);
}

// Block = 256 thr = 4 waves <-> (image b, row r). Wave w covers cols
// {16,16,15,15}. lane = d + 32*kh; lane owns k = kh and kh+2 with all
// constants in VGPRs (loaded once, coalesced). Pixel loop is wave-uniform;
// d-reduction = 4 DPP adds + 1 xor16 shuffle.
__global__ __launch_bounds__(256, 4)
void orientation_main(const float* __restrict__ x,
                      const float4* __restrict__ tb,
                      float* __restrict__ out)
{
    const int tid  = threadIdx.x;
    const int wave = tid >> 6;
    const int lane = tid & 63;
    const int d    = lane & 31;
    const int kh   = lane >> 5;
    const int b    = blockIdx.x / OW;
    const int r    = blockIdx.x - b * OW;

    __shared__ float xs[3][IMG];
    if (tid < 192) {
        const int row = tid >> 6;
        const int col = tid & 63;
        xs[row][col] = x[b * IMG * IMG + (r + row) * IMG + col];
    }

    // own constants -> registers: 16 coalesced dwordx4 loads
    float E0[32], E1[32];
    {
        const float4* t0 = tb + (kh * D + d) * 8;   // k = kh
        const float4* t1 = t0 + 2 * D * 8;          // k = kh + 2
#pragma unroll
        for (int i = 0; i < 8; ++i) {
            *reinterpret_cast<float4*>(&E0[4 * i]) = t0[i];
            *reinterpret_cast<float4*>(&E1[4 * i]) = t1[i];
        }
    }
    __syncthreads();

    const int npx = (wave < 2) ? 16 : 15;                 // 16+16+15+15 = 62
    const int c0  = wave * 16 - ((wave == 3) ? 1 : 0);    // 0,16,32,47

    float acc0 = 0.f, acc1 = 0.f;
    for (int ci = 0; ci < npx; ++ci) {
        const int c = c0 + ci;
        float p[9];
#pragma unroll
        for (int i = 0; i < 3; ++i) {
            p[i * 3 + 0] = xs[i][c + 0];
            p[i * 3 + 1] = xs[i][c + 1];
            p[i * 3 + 2] = xs[i][c + 2];
        }
        const float ctr = p[4];
        float x1f[9];
#pragma unroll
        for (int j = 0; j < 9; ++j)
            x1f[j] = (fabsf(p[j] - ctr) <= 3.0f) ? 1.f : 0.f;

        // binary product (log2 domain): 8 fma per cell
        float logB0 = E0[8], logB1 = E1[8];
        {
            int jj = 0;
#pragma unroll
            for (int j = 0; j < 9; ++j) {
                if (j == 4) continue;
                logB0 = fmaf(x1f[j], E0[jj], logB0);
                logB1 = fmaf(x1f[j], E1[jj], logB1);
                ++jj;
            }
        }
        // analog product: prodA = prod_j (1 + exp2(p*Wc + qc))
        float pA0 = 1.f, pA1 = 1.f;
#pragma unroll
        for (int j = 0; j < 9; ++j) {
            const float a0 = fmaf(p[j], E0[9 + j], E0[18 + j]);
            const float a1 = fmaf(p[j], E1[9 + j], E1[18 + j]);
            pA0 = fmaf(pA0, __builtin_amdgcn_exp2f(a0), pA0);
            pA1 = fmaf(pA1, __builtin_amdgcn_exp2f(a1), pA1);
        }
        float v0 = __builtin_amdgcn_exp2f(logB0) * __builtin_amdgcn_rcpf(pA0);
        float v1 = __builtin_amdgcn_exp2f(logB1) * __builtin_amdgcn_rcpf(pA1);

        // menb = sum over 32 d-lanes: xor1, xor2, xor4, xor8 via DPP, xor16 via shuffle
        v0 = dpp_xadd<0xB1>(v0);   v1 = dpp_xadd<0xB1>(v1);   // quad_perm [1,0,3,2]
        v0 = dpp_xadd<0x4E>(v0);   v1 = dpp_xadd<0x4E>(v1);   // quad_perm [2,3,0,1]
        v0 = dpp_xadd<0x141>(v0);  v1 = dpp_xadd<0x141>(v1);  // row_half_mirror (^7)
        v0 = dpp_xadd<0x140>(v0);  v1 = dpp_xadd<0x140>(v1);  // row_mirror (^15)
        v0 += __shfl_xor(v0, 16, 64);
        v1 += __shfl_xor(v1, 16, 64);

        // soma = sigmoid(10*(menb - 0.5)) = rcp(1 + exp2(-10*log2e*menb + 5*log2e))
        acc0 += __builtin_amdgcn_rcpf(
            1.f + __builtin_amdgcn_exp2f(fmaf(v0, -10.f * LOG2E, 5.f * LOG2E)));
        acc1 += __builtin_amdgcn_rcpf(
            1.f + __builtin_amdgcn_exp2f(fmaf(v1, -10.f * LOG2E, 5.f * LOG2E)));
    }

    // lanes 0 and 32 hold full sums for k = kh and kh+2
    if ((lane & 31) == 0) {
        atomicAdd(&out[b * 4 + kh],     acc0);
        atomicAdd(&out[b * 4 + kh + 2], acc1);
    }
}

extern "C" void kernel_launch(void* const* d_in, const int* in_sizes, int n_in,
                              void* d_out, int out_size, void* d_ws, size_t ws_size,
                              hipStream_t stream) {
    const float* x  = (const float*)d_in[0];
    const float* Wm = (const float*)d_in[1];
    const float* qm = (const float*)d_in[2];
    float* out = (float*)d_out;
    float* tb  = (float*)d_ws;                 // 128 entries * 128 B = 16 KB

    const int B = in_sizes[0] / (IMG * IMG);   // 16

    build_table<<<1, 128, 0, stream>>>(Wm, qm, tb, out, out_size);

    dim3 grid(B * OW);                         // 16 * 62 = 992 blocks
    dim3 block(256);
    orientation_main<<<grid, block, 0, stream>>>(x, (const float4*)tb, out);
}

// Round 7
// 76.903 us; speedup vs baseline: 1.0037x; 1.0037x over previous
//
#include <hip/hip_runtime.h>
#include <math.h>

#define LOG2E 1.44269504088896340736f

constexpr int IMG = 64;   // image stride (64x64)
constexpr int OW  = 62;   // output width/height
constexpr int D   = 32;
constexpr int K   = 4;

// Table: float4 index layout tb4[(k*7 + i)*32 + d], i = 0..6:
//  i0 = {lr0,lr1,lr2,lr3}           lr_j = log2(s1_j/s0_j), binary j in {0,1,2,3,5,6,7,8}
//  i1 = {lr4,lr5,lr6,lr7}
//  i2 = {cB, Wc0, Wc1, Wc2}         cB = sum_j log2(s0_j) + log2(s1_4)
//  i3 = {Wc3,Wc4,Wc5,Wc6}           Wc_j = -10*log2e*W1_j
//  i4 = {Wc7,Wc8,qc0,qc1}           qc_j = +10*log2e*q1_j
//  i5 = {qc2,qc3,qc4,qc5}
//  i6 = {qc6,qc7,qc8,pad}
// Lane d of the main kernel reads tb4[(k*7+i)*32 + d] -> fully coalesced.
__global__ void build_table(const float* __restrict__ Wm,
                            const float* __restrict__ qm,
                            float4* __restrict__ tb4,
                            float* __restrict__ out, int out_n)
{
    const int t = threadIdx.x;
    for (int i = t; i < out_n; i += 128) out[i] = 0.f;   // zero output (replaces memset)
    if (t >= K * D) return;
    const int k = t >> 5;
    const int d = t & 31;
    const int base = d * 72;

    float e[28];
    float cB = 0.f;
    int jj = 0;
#pragma unroll
    for (int j = 0; j < 9; ++j) {
        const float w0 = Wm[base + j * 4 + k];
        const float q0 = qm[base + j * 4 + k];
        const float l1 = -log2f(1.f + expf(-10.f * (w0 - q0)));  // log2 sigmoid(10(W-q))
        if (j == 4) {
            cB += l1;                                            // center flag forced to 1
        } else {
            const float l0 = -log2f(1.f + expf(10.f * q0));      // log2 sigmoid(-10q)
            cB += l0;
            e[jj++] = l1 - l0;                                   // lr
        }
        const float w1 = Wm[base + (9 + j) * 4 + k];
        const float q1 = qm[base + (9 + j) * 4 + k];
        e[9 + j]  = -10.f * LOG2E * w1;                          // Wc
        e[18 + j] =  10.f * LOG2E * q1;                          // qc
    }
    e[8] = cB;
    e[27] = 0.f;
#pragma unroll
    for (int i = 0; i < 7; ++i)
        tb4[(k * 7 + i) * 32 + d] = make_float4(e[4*i], e[4*i+1], e[4*i+2], e[4*i+3]);
}

// butterfly-add stage via DPP; ctrl is a template (compile-time) constant.
template <int CTRL>
__device__ __forceinline__ float dpp_xadd(float v) {
    const int t = __builtin_amdgcn_update_dpp(0, __float_as_int(v), CTRL, 0xf, 0xf, true);
    return v + __int_as_float(t);
}

// one (k,d) cell: logB over binary features + product over analog features.
// All constant operands are components of named float4s -> guaranteed VGPRs.
#define CELL(A0, A1, A2, A3, A4, A5, A6, OUTV)                                         \
    do {                                                                               \
        float logB = A2.x;                                                             \
        logB = fmaf(f0, A0.x, logB);                                                   \
        logB = fmaf(f1, A0.y, logB);                                                   \
        logB = fmaf(f2, A0.z, logB);                                                   \
        logB = fmaf(f3, A0.w, logB);                                                   \
        logB = fmaf(f4, A1.x, logB);                                                   \
        logB = fmaf(f5, A1.y, logB);                                                   \
        logB = fmaf(f6, A1.z, logB);                                                   \
        logB = fmaf(f7, A1.w, logB);                                                   \
        float pA = 1.f, ee;                                                            \
        ee = __builtin_amdgcn_exp2f(fmaf(p0, A2.y, A4.z)); pA = fmaf(pA, ee, pA);      \
        ee = __builtin_amdgcn_exp2f(fmaf(p1, A2.z, A4.w)); pA = fmaf(pA, ee, pA);      \
        ee = __builtin_amdgcn_exp2f(fmaf(p2, A2.w, A5.x)); pA = fmaf(pA, ee, pA);      \
        ee = __builtin_amdgcn_exp2f(fmaf(p3, A3.x, A5.y)); pA = fmaf(pA, ee, pA);      \
        ee = __builtin_amdgcn_exp2f(fmaf(p4, A3.y, A5.z)); pA = fmaf(pA, ee, pA);      \
        ee = __builtin_amdgcn_exp2f(fmaf(p5, A3.z, A5.w)); pA = fmaf(pA, ee, pA);      \
        ee = __builtin_amdgcn_exp2f(fmaf(p6, A3.w, A6.x)); pA = fmaf(pA, ee, pA);      \
        ee = __builtin_amdgcn_exp2f(fmaf(p7, A4.x, A6.y)); pA = fmaf(pA, ee, pA);      \
        ee = __builtin_amdgcn_exp2f(fmaf(p8, A4.y, A6.z)); pA = fmaf(pA, ee, pA);      \
        OUTV = __builtin_amdgcn_exp2f(logB) * __builtin_amdgcn_rcpf(pA);               \
    } while (0)

// Block = 256 thr = 4 waves <-> (image b, row r). Wave w covers cols 16w..16w+15
// (masked at c >= 62). lane = d + 32*kh; lane owns k = kh and kh+2; all 56
// constant floats live in named float4 registers. d-reduction = 4 DPP + 1 shfl.
__global__ __launch_bounds__(256, 4)
void orientation_main(const float* __restrict__ x,
                      const float4* __restrict__ tb4,
                      float* __restrict__ out)
{
    const int tid  = threadIdx.x;
    const int wave = tid >> 6;
    const int lane = tid & 63;
    const int d    = lane & 31;
    const int kh   = lane >> 5;
    const int b    = blockIdx.x / OW;
    const int r    = blockIdx.x - b * OW;

    // constants -> named registers (coalesced: lane d reads element d)
    const float4* ta = tb4 + (kh * 7) * 32 + d;          // k = kh
    const float4* tbp = tb4 + ((kh + 2) * 7) * 32 + d;   // k = kh + 2
    const float4 a0 = ta[0*32],  a1 = ta[1*32],  a2 = ta[2*32],  a3 = ta[3*32];
    const float4 a4 = ta[4*32],  a5 = ta[5*32],  a6 = ta[6*32];
    const float4 b0 = tbp[0*32], b1 = tbp[1*32], b2 = tbp[2*32], b3 = tbp[3*32];
    const float4 b4 = tbp[4*32], b5 = tbp[5*32], b6 = tbp[6*32];

    __shared__ float xs[3][66];
    if (tid < 192) {
        const int row = tid >> 6;
        const int col = tid & 63;
        xs[row][col] = x[b * IMG * IMG + (r + row) * IMG + col];
    }
    if (tid < 6) xs[tid >> 1][64 + (tid & 1)] = 0.f;     // pad cols (masked anyway)
    __syncthreads();

    const int c0 = wave * 16;
    float acc0 = 0.f, acc1 = 0.f;

#pragma unroll 2
    for (int ci = 0; ci < 16; ++ci) {
        const int c = c0 + ci;
        const float p0 = xs[0][c], p1 = xs[0][c+1], p2 = xs[0][c+2];
        const float p3 = xs[1][c], p4 = xs[1][c+1], p5 = xs[1][c+2];
        const float p6 = xs[2][c], p7 = xs[2][c+1], p8 = xs[2][c+2];

        const float ctr = p4;
        const float f0 = (fabsf(p0 - ctr) <= 3.f) ? 1.f : 0.f;
        const float f1 = (fabsf(p1 - ctr) <= 3.f) ? 1.f : 0.f;
        const float f2 = (fabsf(p2 - ctr) <= 3.f) ? 1.f : 0.f;
        const float f3 = (fabsf(p3 - ctr) <= 3.f) ? 1.f : 0.f;
        const float f4 = (fabsf(p5 - ctr) <= 3.f) ? 1.f : 0.f;
        const float f5 = (fabsf(p6 - ctr) <= 3.f) ? 1.f : 0.f;
        const float f6 = (fabsf(p7 - ctr) <= 3.f) ? 1.f : 0.f;
        const float f7 = (fabsf(p8 - ctr) <= 3.f) ? 1.f : 0.f;

        float v0, v1;
        CELL(a0, a1, a2, a3, a4, a5, a6, v0);
        CELL(b0, b1, b2, b3, b4, b5, b6, v1);

        // menb = sum over 32 d-lanes: masks {1,2,7,15,16} span the 32-group
        v0 = dpp_xadd<0xB1>(v0);   v1 = dpp_xadd<0xB1>(v1);   // quad_perm xor1
        v0 = dpp_xadd<0x4E>(v0);   v1 = dpp_xadd<0x4E>(v1);   // quad_perm xor2
        v0 = dpp_xadd<0x141>(v0);  v1 = dpp_xadd<0x141>(v1);  // row_half_mirror (xor7)
        v0 = dpp_xadd<0x140>(v0);  v1 = dpp_xadd<0x140>(v1);  // row_mirror (xor15)
        v0 += __shfl_xor(v0, 16, 64);
        v1 += __shfl_xor(v1, 16, 64);

        // soma = sigmoid(10*(menb-0.5)) = rcp(1 + exp2(-10*log2e*menb + 5*log2e))
        const float s0 = __builtin_amdgcn_rcpf(
            1.f + __builtin_amdgcn_exp2f(fmaf(v0, -10.f * LOG2E, 5.f * LOG2E)));
        const float s1 = __builtin_amdgcn_rcpf(
            1.f + __builtin_amdgcn_exp2f(fmaf(v1, -10.f * LOG2E, 5.f * LOG2E)));
        if (c < OW) { acc0 += s0; acc1 += s1; }
    }

    // lanes 0 and 32 hold full sums for k = kh and kh+2
    if ((lane & 31) == 0) {
        atomicAdd(&out[b * 4 + kh],     acc0);
        atomicAdd(&out[b * 4 + kh + 2], acc1);
    }
}

extern "C" void kernel_launch(void* const* d_in, const int* in_sizes, int n_in,
                              void* d_out, int out_size, void* d_ws, size_t ws_size,
                              hipStream_t stream) {
    const float* x  = (const float*)d_in[0];
    const float* Wm = (const float*)d_in[1];
    const float* qm = (const float*)d_in[2];
    float* out = (float*)d_out;
    float4* tb4 = (float4*)d_ws;               // 4*7*32 float4 = 14336 B

    const int B = in_sizes[0] / (IMG * IMG);   // 16

    build_table<<<1, 128, 0, stream>>>(Wm, qm, tb4, out, out_size);

    dim3 grid(B * OW);                         // 16 * 62 = 992 blocks
    dim3 block(256);
    orientation_main<<<grid, block, 0, stream>>>(x, tb4, out);
}

// Round 8
// 75.178 us; speedup vs baseline: 1.0268x; 1.0229x over previous
//
#include <hip/hip_runtime.h>
#include <math.h>

#define LOG2E 1.44269504088896340736f

constexpr int IMG = 64;   // image stride (64x64)
constexpr int OW  = 62;   // output width/height
constexpr int D   = 32;
constexpr int K   = 4;

// Table: float4 index layout tb4[(k*7 + i)*32 + d], i = 0..6:
//  i0 = {lr0,lr1,lr2,lr3}           lr_j = log2(s1_j/s0_j), binary j in {0,1,2,3,5,6,7,8}
//  i1 = {lr4,lr5,lr6,lr7}
//  i2 = {cB, Wc0, Wc1, Wc2}         cB = sum_j log2(s0_j) + log2(s1_4)
//  i3 = {Wc3,Wc4,Wc5,Wc6}           Wc_j = -10*log2e*W1_j
//  i4 = {Wc7,Wc8,qc0,qc1}           qc_j = +10*log2e*q1_j
//  i5 = {qc2,qc3,qc4,qc5}
//  i6 = {qc6,qc7,qc8,pad}
__global__ void build_table(const float* __restrict__ Wm,
                            const float* __restrict__ qm,
                            float4* __restrict__ tb4,
                            float* __restrict__ out, int out_n)
{
    const int t = threadIdx.x;
    for (int i = t; i < out_n; i += 128) out[i] = 0.f;   // zero output (replaces memset)
    if (t >= K * D) return;
    const int k = t >> 5;
    const int d = t & 31;
    const int base = d * 72;

    float e[28];
    float cB = 0.f;
    int jj = 0;
#pragma unroll
    for (int j = 0; j < 9; ++j) {
        const float w0 = Wm[base + j * 4 + k];
        const float q0 = qm[base + j * 4 + k];
        const float l1 = -log2f(1.f + expf(-10.f * (w0 - q0)));  // log2 sigmoid(10(W-q))
        if (j == 4) {
            cB += l1;                                            // center flag forced to 1
        } else {
            const float l0 = -log2f(1.f + expf(10.f * q0));      // log2 sigmoid(-10q)
            cB += l0;
            e[jj++] = l1 - l0;                                   // lr
        }
        const float w1 = Wm[base + (9 + j) * 4 + k];
        const float q1 = qm[base + (9 + j) * 4 + k];
        e[9 + j]  = -10.f * LOG2E * w1;                          // Wc
        e[18 + j] =  10.f * LOG2E * q1;                          // qc
    }
    e[8] = cB;
    e[27] = 0.f;
#pragma unroll
    for (int i = 0; i < 7; ++i)
        tb4[(k * 7 + i) * 32 + d] = make_float4(e[4*i], e[4*i+1], e[4*i+2], e[4*i+3]);
}

// butterfly-add stage via DPP; ctrl is a template (compile-time) constant.
template <int CTRL>
__device__ __forceinline__ float dpp_xadd(float v) {
    const int t = __builtin_amdgcn_update_dpp(0, __float_as_int(v), CTRL, 0xf, 0xf, true);
    return v + __int_as_float(t);
}

// Opaque register pin: the compiler cannot rematerialize an asm result, so the
// pinned value MUST stay live in VGPRs across the loop (prevents the
// register-pressure heuristic from sinking the constant loads into the loop,
// which is what produced VGPR_Count=44 / 72us in rounds 5 and 7).
#define PIN4(v) asm volatile("" : "+v"(v.x), "+v"(v.y), "+v"(v.z), "+v"(v.w))

// one (k,d) cell: logB over binary features + product over analog features.
#define CELL(A0, A1, A2, A3, A4, A5, A6, OUTV)                                         \
    do {                                                                               \
        float logB = A2.x;                                                             \
        logB = fmaf(f0, A0.x, logB);                                                   \
        logB = fmaf(f1, A0.y, logB);                                                   \
        logB = fmaf(f2, A0.z, logB);                                                   \
        logB = fmaf(f3, A0.w, logB);                                                   \
        logB = fmaf(f4, A1.x, logB);                                                   \
        logB = fmaf(f5, A1.y, logB);                                                   \
        logB = fmaf(f6, A1.z, logB);                                                   \
        logB = fmaf(f7, A1.w, logB);                                                   \
        float pA = 1.f, ee;                                                            \
        ee = __builtin_amdgcn_exp2f(fmaf(p0, A2.y, A4.z)); pA = fmaf(pA, ee, pA);      \
        ee = __builtin_amdgcn_exp2f(fmaf(p1, A2.z, A4.w)); pA = fmaf(pA, ee, pA);      \
        ee = __builtin_amdgcn_exp2f(fmaf(p2, A2.w, A5.x)); pA = fmaf(pA, ee, pA);      \
        ee = __builtin_amdgcn_exp2f(fmaf(p3, A3.x, A5.y)); pA = fmaf(pA, ee, pA);      \
        ee = __builtin_amdgcn_exp2f(fmaf(p4, A3.y, A5.z)); pA = fmaf(pA, ee, pA);      \
        ee = __builtin_amdgcn_exp2f(fmaf(p5, A3.z, A5.w)); pA = fmaf(pA, ee, pA);      \
        ee = __builtin_amdgcn_exp2f(fmaf(p6, A3.w, A6.x)); pA = fmaf(pA, ee, pA);      \
        ee = __builtin_amdgcn_exp2f(fmaf(p7, A4.x, A6.y)); pA = fmaf(pA, ee, pA);      \
        ee = __builtin_amdgcn_exp2f(fmaf(p8, A4.y, A6.z)); pA = fmaf(pA, ee, pA);      \
        OUTV = __builtin_amdgcn_exp2f(logB) * __builtin_amdgcn_rcpf(pA);               \
    } while (0)

// Block = 256 thr = 4 waves <-> (image b, row r). Wave w covers cols 16w..16w+15
// (masked at c >= 62). lane = d + 32*kh; lane owns k = kh and kh+2; all 56
// constant floats pinned in VGPRs. d-reduction = 4 DPP + 1 shfl.
__global__ __launch_bounds__(256, 4)
void orientation_main(const float* __restrict__ x,
                      const float4* __restrict__ tb4,
                      float* __restrict__ out)
{
    const int tid  = threadIdx.x;
    const int wave = tid >> 6;
    const int lane = tid & 63;
    const int d    = lane & 31;
    const int kh   = lane >> 5;
    const int b    = blockIdx.x / OW;
    const int r    = blockIdx.x - b * OW;

    // constants -> named registers (coalesced: lane d reads element d)
    const float4* ta  = tb4 + (kh * 7) * 32 + d;         // k = kh
    const float4* tbp = tb4 + ((kh + 2) * 7) * 32 + d;   // k = kh + 2
    float4 a0 = ta[0*32],  a1 = ta[1*32],  a2 = ta[2*32],  a3 = ta[3*32];
    float4 a4 = ta[4*32],  a5 = ta[5*32],  a6 = ta[6*32];
    float4 b0 = tbp[0*32], b1 = tbp[1*32], b2 = tbp[2*32], b3 = tbp[3*32];
    float4 b4 = tbp[4*32], b5 = tbp[5*32], b6 = tbp[6*32];
    PIN4(a0); PIN4(a1); PIN4(a2); PIN4(a3); PIN4(a4); PIN4(a5); PIN4(a6);
    PIN4(b0); PIN4(b1); PIN4(b2); PIN4(b3); PIN4(b4); PIN4(b5); PIN4(b6);

    __shared__ float xs[3][66];
    if (tid < 192) {
        const int row = tid >> 6;
        const int col = tid & 63;
        xs[row][col] = x[b * IMG * IMG + (r + row) * IMG + col];
    }
    if (tid < 6) xs[tid >> 1][64 + (tid & 1)] = 0.f;     // pad cols (masked anyway)
    __syncthreads();

    const int c0 = wave * 16;
    float acc0 = 0.f, acc1 = 0.f;

#pragma unroll 2
    for (int ci = 0; ci < 16; ++ci) {
        const int c = c0 + ci;
        const float p0 = xs[0][c], p1 = xs[0][c+1], p2 = xs[0][c+2];
        const float p3 = xs[1][c], p4 = xs[1][c+1], p5 = xs[1][c+2];
        const float p6 = xs[2][c], p7 = xs[2][c+1], p8 = xs[2][c+2];

        const float ctr = p4;
        const float f0 = (fabsf(p0 - ctr) <= 3.f) ? 1.f : 0.f;
        const float f1 = (fabsf(p1 - ctr) <= 3.f) ? 1.f : 0.f;
        const float f2 = (fabsf(p2 - ctr) <= 3.f) ? 1.f : 0.f;
        const float f3 = (fabsf(p3 - ctr) <= 3.f) ? 1.f : 0.f;
        const float f4 = (fabsf(p5 - ctr) <= 3.f) ? 1.f : 0.f;
        const float f5 = (fabsf(p6 - ctr) <= 3.f) ? 1.f : 0.f;
        const float f6 = (fabsf(p7 - ctr) <= 3.f) ? 1.f : 0.f;
        const float f7 = (fabsf(p8 - ctr) <= 3.f) ? 1.f : 0.f;

        float v0, v1;
        CELL(a0, a1, a2, a3, a4, a5, a6, v0);
        CELL(b0, b1, b2, b3, b4, b5, b6, v1);

        // menb = sum over 32 d-lanes: masks {1,2,7,15,16} span the 32-group
        v0 = dpp_xadd<0xB1>(v0);   v1 = dpp_xadd<0xB1>(v1);   // quad_perm xor1
        v0 = dpp_xadd<0x4E>(v0);   v1 = dpp_xadd<0x4E>(v1);   // quad_perm xor2
        v0 = dpp_xadd<0x141>(v0);  v1 = dpp_xadd<0x141>(v1);  // row_half_mirror (xor7)
        v0 = dpp_xadd<0x140>(v0);  v1 = dpp_xadd<0x140>(v1);  // row_mirror (xor15)
        v0 += __shfl_xor(v0, 16, 64);
        v1 += __shfl_xor(v1, 16, 64);

        // soma = sigmoid(10*(menb-0.5)) = rcp(1 + exp2(-10*log2e*menb + 5*log2e))
        const float s0 = __builtin_amdgcn_rcpf(
            1.f + __builtin_amdgcn_exp2f(fmaf(v0, -10.f * LOG2E, 5.f * LOG2E)));
        const float s1 = __builtin_amdgcn_rcpf(
            1.f + __builtin_amdgcn_exp2f(fmaf(v1, -10.f * LOG2E, 5.f * LOG2E)));
        if (c < OW) { acc0 += s0; acc1 += s1; }
    }

    // lanes 0 and 32 hold full sums for k = kh and kh+2
    if ((lane & 31) == 0) {
        atomicAdd(&out[b * 4 + kh],     acc0);
        atomicAdd(&out[b * 4 + kh + 2], acc1);
    }
}

extern "C" void kernel_launch(void* const* d_in, const int* in_sizes, int n_in,
                              void* d_out, int out_size, void* d_ws, size_t ws_size,
                              hipStream_t stream) {
    const float* x  = (const float*)d_in[0];
    const float* Wm = (const float*)d_in[1];
    const float* qm = (const float*)d_in[2];
    float* out = (float*)d_out;
    float4* tb4 = (float4*)d_ws;               // 4*7*32 float4 = 14336 B

    const int B = in_sizes[0] / (IMG * IMG);   // 16

    build_table<<<1, 128, 0, stream>>>(Wm, qm, tb4, out, out_size);

    dim3 grid(B * OW);                         // 16 * 62 = 992 blocks
    dim3 block(256);
    orientation_main<<<grid, block, 0, stream>>>(x, tb4, out);
}

// Round 9
// 73.325 us; speedup vs baseline: 1.0527x; 1.0253x over previous
//
#include <hip/hip_runtime.h>
#include <math.h>

#define LOG2E 1.44269504088896340736f

constexpr int IMG = 64;   // image stride (64x64)
constexpr int OW  = 62;   // output width/height
constexpr int D   = 32;
constexpr int K   = 4;

// Table: float4 index layout tb4[(k*7 + i)*32 + d], i = 0..6:
//  i0 = {lr0,lr1,lr2,lr3}           lr_j = log2(s1_j/s0_j), binary j in {0,1,2,3,5,6,7,8}
//  i1 = {lr4,lr5,lr6,lr7}
//  i2 = {cB, Wc0, Wc1, Wc2}         cB = sum_j log2(s0_j) + log2(s1_4)
//  i3 = {Wc3,Wc4,Wc5,Wc6}           Wc_j = -10*log2e*W1_j
//  i4 = {Wc7,Wc8,qc0,qc1}           qc_j = +10*log2e*q1_j
//  i5 = {qc2,qc3,qc4,qc5}
//  i6 = {qc6,qc7,qc8,pad}
__global__ void build_table(const float* __restrict__ Wm,
                            const float* __restrict__ qm,
                            float4* __restrict__ tb4,
                            float* __restrict__ out, int out_n)
{
    const int t = threadIdx.x;
    for (int i = t; i < out_n; i += 128) out[i] = 0.f;   // zero output (replaces memset)
    if (t >= K * D) return;
    const int k = t >> 5;
    const int d = t & 31;
    const int base = d * 72;

    float e[28];
    float cB = 0.f;
    int jj = 0;
#pragma unroll
    for (int j = 0; j < 9; ++j) {
        const float w0 = Wm[base + j * 4 + k];
        const float q0 = qm[base + j * 4 + k];
        const float l1 = -log2f(1.f + expf(-10.f * (w0 - q0)));  // log2 sigmoid(10(W-q))
        if (j == 4) {
            cB += l1;                                            // center flag forced to 1
        } else {
            const float l0 = -log2f(1.f + expf(10.f * q0));      // log2 sigmoid(-10q)
            cB += l0;
            e[jj++] = l1 - l0;                                   // lr
        }
        const float w1 = Wm[base + (9 + j) * 4 + k];
        const float q1 = qm[base + (9 + j) * 4 + k];
        e[9 + j]  = -10.f * LOG2E * w1;                          // Wc
        e[18 + j] =  10.f * LOG2E * q1;                          // qc
    }
    e[8] = cB;
    e[27] = 0.f;
#pragma unroll
    for (int i = 0; i < 7; ++i)
        tb4[(k * 7 + i) * 32 + d] = make_float4(e[4*i], e[4*i+1], e[4*i+2], e[4*i+3]);
}

// butterfly-add stage via DPP; ctrl is a template (compile-time) constant.
template <int CTRL>
__device__ __forceinline__ float dpp_xadd(float v) {
    const int t = __builtin_amdgcn_update_dpp(0, __float_as_int(v), CTRL, 0xf, 0xf, true);
    return v + __int_as_float(t);
}

// Opaque register pin (cannot be rematerialized; with the relaxed occupancy
// target below the values also won't be spilled).
#define PIN4(v) asm volatile("" : "+v"(v.x), "+v"(v.y), "+v"(v.z), "+v"(v.w))

// one (k,d) cell: logB over binary features + product over analog features.
#define CELL(A0, A1, A2, A3, A4, A5, A6, OUTV)                                         \
    do {                                                                               \
        float logB = A2.x;                                                             \
        logB = fmaf(f0, A0.x, logB);                                                   \
        logB = fmaf(f1, A0.y, logB);                                                   \
        logB = fmaf(f2, A0.z, logB);                                                   \
        logB = fmaf(f3, A0.w, logB);                                                   \
        logB = fmaf(f4, A1.x, logB);                                                   \
        logB = fmaf(f5, A1.y, logB);                                                   \
        logB = fmaf(f6, A1.z, logB);                                                   \
        logB = fmaf(f7, A1.w, logB);                                                   \
        float pA = 1.f, ee;                                                            \
        ee = __builtin_amdgcn_exp2f(fmaf(p0, A2.y, A4.z)); pA = fmaf(pA, ee, pA);      \
        ee = __builtin_amdgcn_exp2f(fmaf(p1, A2.z, A4.w)); pA = fmaf(pA, ee, pA);      \
        ee = __builtin_amdgcn_exp2f(fmaf(p2, A2.w, A5.x)); pA = fmaf(pA, ee, pA);      \
        ee = __builtin_amdgcn_exp2f(fmaf(p3, A3.x, A5.y)); pA = fmaf(pA, ee, pA);      \
        ee = __builtin_amdgcn_exp2f(fmaf(p4, A3.y, A5.z)); pA = fmaf(pA, ee, pA);      \
        ee = __builtin_amdgcn_exp2f(fmaf(p5, A3.z, A5.w)); pA = fmaf(pA, ee, pA);      \
        ee = __builtin_amdgcn_exp2f(fmaf(p6, A3.w, A6.x)); pA = fmaf(pA, ee, pA);      \
        ee = __builtin_amdgcn_exp2f(fmaf(p7, A4.x, A6.y)); pA = fmaf(pA, ee, pA);      \
        ee = __builtin_amdgcn_exp2f(fmaf(p8, A4.y, A6.z)); pA = fmaf(pA, ee, pA);      \
        OUTV = __builtin_amdgcn_exp2f(logB) * __builtin_amdgcn_rcpf(pA);               \
    } while (0)

// Block = 256 thr = 4 waves <-> (image b, row r). Wave w covers cols 16w..16w+15
// (masked at c >= 62). lane = d + 32*kh; lane owns k = kh and kh+2.
// amdgpu_waves_per_eu(2,4): grid is 3.875 blocks/CU (~4 waves/EU max), so cap
// the compiler's occupancy target at 4 -> VGPR budget 128 -> constants stay
// register-resident (rounds 5/7/8: compiler chased 8 waves/EU, spilled to 44
// VGPRs, and re-loaded constants every pixel -> 69-72 us @ VALUBusy 20%).
__global__ __attribute__((amdgpu_flat_work_group_size(256, 256)))
           __attribute__((amdgpu_waves_per_eu(2, 4)))
void orientation_main(const float* __restrict__ x,
                      const float4* __restrict__ tb4,
                      float* __restrict__ out)
{
    const int tid  = threadIdx.x;
    const int wave = tid >> 6;
    const int lane = tid & 63;
    const int d    = lane & 31;
    const int kh   = lane >> 5;
    const int b    = blockIdx.x / OW;
    const int r    = blockIdx.x - b * OW;

    // constants -> named registers (coalesced: lane d reads element d)
    const float4* ta  = tb4 + (kh * 7) * 32 + d;         // k = kh
    const float4* tbp = tb4 + ((kh + 2) * 7) * 32 + d;   // k = kh + 2
    float4 a0 = ta[0*32],  a1 = ta[1*32],  a2 = ta[2*32],  a3 = ta[3*32];
    float4 a4 = ta[4*32],  a5 = ta[5*32],  a6 = ta[6*32];
    float4 b0 = tbp[0*32], b1 = tbp[1*32], b2 = tbp[2*32], b3 = tbp[3*32];
    float4 b4 = tbp[4*32], b5 = tbp[5*32], b6 = tbp[6*32];
    PIN4(a0); PIN4(a1); PIN4(a2); PIN4(a3); PIN4(a4); PIN4(a5); PIN4(a6);
    PIN4(b0); PIN4(b1); PIN4(b2); PIN4(b3); PIN4(b4); PIN4(b5); PIN4(b6);

    __shared__ float xs[3][66];
    if (tid < 192) {
        const int row = tid >> 6;
        const int col = tid & 63;
        xs[row][col] = x[b * IMG * IMG + (r + row) * IMG + col];
    }
    if (tid < 6) xs[tid >> 1][64 + (tid & 1)] = 0.f;     // pad cols (masked anyway)
    __syncthreads();

    const int c0 = wave * 16;
    float acc0 = 0.f, acc1 = 0.f;

#pragma unroll 2
    for (int ci = 0; ci < 16; ++ci) {
        const int c = c0 + ci;
        const float p0 = xs[0][c], p1 = xs[0][c+1], p2 = xs[0][c+2];
        const float p3 = xs[1][c], p4 = xs[1][c+1], p5 = xs[1][c+2];
        const float p6 = xs[2][c], p7 = xs[2][c+1], p8 = xs[2][c+2];

        const float ctr = p4;
        const float f0 = (fabsf(p0 - ctr) <= 3.f) ? 1.f : 0.f;
        const float f1 = (fabsf(p1 - ctr) <= 3.f) ? 1.f : 0.f;
        const float f2 = (fabsf(p2 - ctr) <= 3.f) ? 1.f : 0.f;
        const float f3 = (fabsf(p3 - ctr) <= 3.f) ? 1.f : 0.f;
        const float f4 = (fabsf(p5 - ctr) <= 3.f) ? 1.f : 0.f;
        const float f5 = (fabsf(p6 - ctr) <= 3.f) ? 1.f : 0.f;
        const float f6 = (fabsf(p7 - ctr) <= 3.f) ? 1.f : 0.f;
        const float f7 = (fabsf(p8 - ctr) <= 3.f) ? 1.f : 0.f;

        float v0, v1;
        CELL(a0, a1, a2, a3, a4, a5, a6, v0);
        CELL(b0, b1, b2, b3, b4, b5, b6, v1);

        // menb = sum over 32 d-lanes: masks {1,2,7,15,16} span the 32-group
        v0 = dpp_xadd<0xB1>(v0);   v1 = dpp_xadd<0xB1>(v1);   // quad_perm xor1
        v0 = dpp_xadd<0x4E>(v0);   v1 = dpp_xadd<0x4E>(v1);   // quad_perm xor2
        v0 = dpp_xadd<0x141>(v0);  v1 = dpp_xadd<0x141>(v1);  // row_half_mirror (xor7)
        v0 = dpp_xadd<0x140>(v0);  v1 = dpp_xadd<0x140>(v1);  // row_mirror (xor15)
        v0 += __shfl_xor(v0, 16, 64);
        v1 += __shfl_xor(v1, 16, 64);

        // soma = sigmoid(10*(menb-0.5)) = rcp(1 + exp2(-10*log2e*menb + 5*log2e))
        const float s0 = __builtin_amdgcn_rcpf(
            1.f + __builtin_amdgcn_exp2f(fmaf(v0, -10.f * LOG2E, 5.f * LOG2E)));
        const float s1 = __builtin_amdgcn_rcpf(
            1.f + __builtin_amdgcn_exp2f(fmaf(v1, -10.f * LOG2E, 5.f * LOG2E)));
        if (c < OW) { acc0 += s0; acc1 += s1; }
    }

    // lanes 0 and 32 hold full sums for k = kh and kh+2
    if ((lane & 31) == 0) {
        atomicAdd(&out[b * 4 + kh],     acc0);
        atomicAdd(&out[b * 4 + kh + 2], acc1);
    }
}

extern "C" void kernel_launch(void* const* d_in, const int* in_sizes, int n_in,
                              void* d_out, int out_size, void* d_ws, size_t ws_size,
                              hipStream_t stream) {
    const float* x  = (const float*)d_in[0];
    const float* Wm = (const float*)d_in[1];
    const float* qm = (const float*)d_in[2];
    float* out = (float*)d_out;
    float4* tb4 = (float4*)d_ws;               // 4*7*32 float4 = 14336 B

    const int B = in_sizes[0] / (IMG * IMG);   // 16

    build_table<<<1, 128, 0, stream>>>(Wm, qm, tb4, out, out_size);

    dim3 grid(B * OW);                         // 16 * 62 = 992 blocks
    dim3 block(256);
    orientation_main<<<grid, block, 0, stream>>>(x, tb4, out);
}

// Round 10
// 45.869 us; speedup vs baseline: 1.6828x; 1.5986x over previous
//
#include <hip/hip_runtime.h>
#include <math.h>

#define LOG2E 1.44269504088896340736f

typedef int v8i __attribute__((ext_vector_type(8)));
typedef int v4i __attribute__((ext_vector_type(4)));

constexpr int IMG = 64;   // image stride (64x64)
constexpr int OW  = 62;   // output width/height
constexpr int D   = 32;
constexpr int K   = 4;

// Table entry (cell t = k*32 + d), stride 32 floats (128 B):
//  [0..7]   lr[8] = log2(s1_j/s0_j), binary j in {0,1,2,3,5,6,7,8}
//  [8]      cB    = sum_j log2(s0_j) + log2(s1_4)   (center forced to 1)
//  [9..17]  Wc[j] = -10*log2e*W1_j                  (analog)
//  [18..26] Q[j]  = exp(10*q1_j)  ( = 2^(qc_j) )
//  [27..31] pad
__global__ void build_table(const float* __restrict__ Wm,
                            const float* __restrict__ qm,
                            float* __restrict__ tb,
                            float* __restrict__ out, int out_n)
{
    const int t = threadIdx.x;
    for (int i = t; i < out_n; i += 128) out[i] = 0.f;   // zero output (replaces memset)
    if (t >= K * D) return;
    const int k = t >> 5;
    const int d = t & 31;
    const int base = d * 72;
    float* e = tb + t * 32;

    float cB = 0.f;
    int jj = 0;
#pragma unroll
    for (int j = 0; j < 9; ++j) {
        const float w0 = Wm[base + j * 4 + k];
        const float q0 = qm[base + j * 4 + k];
        const float l1 = -log2f(1.f + expf(-10.f * (w0 - q0)));  // log2 sigmoid(10(W-q))
        if (j == 4) {
            cB += l1;                                            // center flag forced to 1
        } else {
            const float l0 = -log2f(1.f + expf(10.f * q0));      // log2 sigmoid(-10q)
            cB += l0;
            e[jj++] = l1 - l0;                                   // lr
        }
        const float w1 = Wm[base + (9 + j) * 4 + k];
        const float q1 = qm[base + (9 + j) * 4 + k];
        e[9 + j]  = -10.f * LOG2E * w1;                          // Wc
        e[18 + j] = expf(10.f * q1);                             // Q = 2^qc
    }
    e[8] = cB;
    e[27] = e[28] = e[29] = e[30] = e[31] = 0.f;
}

// 28-dword wave-uniform fetch on the SCALAR pipe (guaranteed s_load).
__device__ __forceinline__ void sload(uint64_t tp, v8i& A, v8i& B, v8i& C, v4i& Dv) {
    asm volatile("s_load_dwordx8 %0, %4, 0x0\n\t"
                 "s_load_dwordx8 %1, %4, 0x20\n\t"
                 "s_load_dwordx8 %2, %4, 0x40\n\t"
                 "s_load_dwordx4 %3, %4, 0x60"
                 : "=&s"(A), "=&s"(B), "=&s"(C), "=&s"(Dv)
                 : "s"(tp));
}
// Wait with data-ties: later uses are data-ordered after the wait.
__device__ __forceinline__ void swait(v8i& A, v8i& B, v8i& C, v4i& Dv) {
    asm volatile("s_waitcnt lgkmcnt(0)"
                 : "+s"(A), "+s"(B), "+s"(C), "+s"(Dv));
}

#define ITF(v) __int_as_float(v)

// one (k,d) cell over the wave's 64 pixels; every VALU op has <=1 SGPR operand.
// A = lr0..7; B = cB,Wc0..6; C = Wc7,Wc8,Q0..5; Dv = Q6,Q7,Q8,pad
#define STEP(Av, Bv, Cv, Dv)                                                      \
    do {                                                                          \
        float logB = ITF(Bv[0]);                                                  \
        logB = fmaf(f[0], ITF(Av[0]), logB);                                      \
        logB = fmaf(f[1], ITF(Av[1]), logB);                                      \
        logB = fmaf(f[2], ITF(Av[2]), logB);                                      \
        logB = fmaf(f[3], ITF(Av[3]), logB);                                      \
        logB = fmaf(f[4], ITF(Av[4]), logB);                                      \
        logB = fmaf(f[5], ITF(Av[5]), logB);                                      \
        logB = fmaf(f[6], ITF(Av[6]), logB);                                      \
        logB = fmaf(f[7], ITF(Av[7]), logB);                                      \
        float pA = 1.f, ee;                                                       \
        ee = __builtin_amdgcn_exp2f(p[0] * ITF(Bv[1])); pA = fmaf(pA * ee, ITF(Cv[2]), pA); \
        ee = __builtin_amdgcn_exp2f(p[1] * ITF(Bv[2])); pA = fmaf(pA * ee, ITF(Cv[3]), pA); \
        ee = __builtin_amdgcn_exp2f(p[2] * ITF(Bv[3])); pA = fmaf(pA * ee, ITF(Cv[4]), pA); \
        ee = __builtin_amdgcn_exp2f(p[3] * ITF(Bv[4])); pA = fmaf(pA * ee, ITF(Cv[5]), pA); \
        ee = __builtin_amdgcn_exp2f(p[4] * ITF(Bv[5])); pA = fmaf(pA * ee, ITF(Cv[6]), pA); \
        ee = __builtin_amdgcn_exp2f(p[5] * ITF(Bv[6])); pA = fmaf(pA * ee, ITF(Cv[7]), pA); \
        ee = __builtin_amdgcn_exp2f(p[6] * ITF(Bv[7])); pA = fmaf(pA * ee, ITF(Dv[0]), pA); \
        ee = __builtin_amdgcn_exp2f(p[7] * ITF(Cv[0])); pA = fmaf(pA * ee, ITF(Dv[1]), pA); \
        ee = __builtin_amdgcn_exp2f(p[8] * ITF(Cv[1])); pA = fmaf(pA * ee, ITF(Dv[2]), pA); \
        menb = fmaf(__builtin_amdgcn_exp2f(logB), __builtin_amdgcn_rcpf(pA), menb); \
    } while (0)

// Block = 1024 thr = 16 waves <-> (image b, row r). lane = pixel column.
// Wave w: k = w&3, d-group = w>>2 (8 cells, streamed via scalar loads).
// Per-thread VGPR state is tiny (p[9], f[8], menb) -> nothing to spill.
// menb summed over d-groups through LDS; waves 0..3 finish soma + reduce.
__global__ __launch_bounds__(1024)
void orientation_main(const float* __restrict__ x,
                      const float* __restrict__ tb,
                      float* __restrict__ out)
{
    const int tid  = threadIdx.x;
    const int lane = tid & 63;
    const int wv   = __builtin_amdgcn_readfirstlane(tid >> 6);
    const int kk   = wv & 3;
    const int dg   = wv >> 2;
    const int b    = blockIdx.x / OW;
    const int r    = blockIdx.x - b * OW;

    __shared__ float xs[3][66];
    __shared__ float menb_lds[16][64];

    if (tid < 192) {
        const int row = tid >> 6;
        const int col = tid & 63;
        xs[row][col] = x[b * IMG * IMG + (r + row) * IMG + col];
    }
    if (tid < 6) xs[tid >> 1][64 + (tid & 1)] = 0.f;     // pad (lanes 62/63 masked later)
    __syncthreads();

    const int c = lane;
    float p[9];
    p[0] = xs[0][c]; p[1] = xs[0][c+1]; p[2] = xs[0][c+2];
    p[3] = xs[1][c]; p[4] = xs[1][c+1]; p[5] = xs[1][c+2];
    p[6] = xs[2][c]; p[7] = xs[2][c+1]; p[8] = xs[2][c+2];

    const float ctr = p[4];
    float f[8];
    f[0] = (fabsf(p[0] - ctr) <= 3.f) ? 1.f : 0.f;
    f[1] = (fabsf(p[1] - ctr) <= 3.f) ? 1.f : 0.f;
    f[2] = (fabsf(p[2] - ctr) <= 3.f) ? 1.f : 0.f;
    f[3] = (fabsf(p[3] - ctr) <= 3.f) ? 1.f : 0.f;
    f[4] = (fabsf(p[5] - ctr) <= 3.f) ? 1.f : 0.f;
    f[5] = (fabsf(p[6] - ctr) <= 3.f) ? 1.f : 0.f;
    f[6] = (fabsf(p[7] - ctr) <= 3.f) ? 1.f : 0.f;
    f[7] = (fabsf(p[8] - ctr) <= 3.f) ? 1.f : 0.f;

    // 8 cells: table bytes [base, base + 8*128), clamped prefetch stays inside
    uint64_t tp = (uint64_t)tb + (uint64_t)(kk * 32 + dg * 8) * 128u;
    v8i A0, B0, C0, A1, B1, C1;
    v4i D0, D1;

    sload(tp, A0, B0, C0, D0);
    float menb = 0.f;
#pragma unroll
    for (int i = 0; i < 8; i += 2) {
        const uint64_t tn1 = tp + 0x80;
        const uint64_t tn2 = (i < 6) ? tp + 0x100 : tp;   // clamp last prefetch (in-bounds)
        swait(A0, B0, C0, D0);
        sload(tn1, A1, B1, C1, D1);
        STEP(A0, B0, C0, D0);
        swait(A1, B1, C1, D1);
        sload(tn2, A0, B0, C0, D0);
        STEP(A1, B1, C1, D1);
        tp += 0x100;
    }

    menb_lds[wv][lane] = menb;
    __syncthreads();

    if (wv < 4) {   // wave wv handles k = wv
        const float m = menb_lds[wv][lane] + menb_lds[4 + wv][lane] +
                        menb_lds[8 + wv][lane] + menb_lds[12 + wv][lane];
        // soma = sigmoid(10*(m-0.5)) = rcp(1 + exp2(-10*log2e*m + 5*log2e))
        float soma = __builtin_amdgcn_rcpf(
            1.f + __builtin_amdgcn_exp2f(fmaf(m, -10.f * LOG2E, 5.f * LOG2E)));
        if (lane >= OW) soma = 0.f;
#pragma unroll
        for (int mm = 1; mm <= 32; mm <<= 1)
            soma += __shfl_xor(soma, mm, 64);
        if (lane == 0)
            atomicAdd(&out[b * 4 + wv], soma);
    }
}

extern "C" void kernel_launch(void* const* d_in, const int* in_sizes, int n_in,
                              void* d_out, int out_size, void* d_ws, size_t ws_size,
                              hipStream_t stream) {
    const float* x  = (const float*)d_in[0];
    const float* Wm = (const float*)d_in[1];
    const float* qm = (const float*)d_in[2];
    float* out = (float*)d_out;
    float* tb  = (float*)d_ws;                 // 128 cells * 128 B = 16 KB

    const int B = in_sizes[0] / (IMG * IMG);   // 16

    build_table<<<1, 128, 0, stream>>>(Wm, qm, tb, out, out_size);

    dim3 grid(B * OW);                         // 16 * 62 = 992 blocks
    dim3 block(1024);                          // 16 waves
    orientation_main<<<grid, block, 0, stream>>>(x, tb, out);
}